// Round 3
// baseline (553.418 us; speedup 1.0000x reference)
//
#include <hip/hip_runtime.h>

// MaxPool2d 2x2 stride 2 on (32, 64, 224, 224) fp32 -> (32, 64, 112, 112).
// SAME padding is zero (224 even), so each output = max over a disjoint 2x2.
//
// R2 change: fully-contiguous per-instruction loads. Planes are contiguous,
// so the input is just 458752 rows x 224 floats; row-pair r == global input
// rows {2r, 2r+1}. Work item idx = r*56 + c:
//   loads  float4 in[4*idx + 224*r]  (row 2r)   -- lane stride 16 B, coalesced
//          float4 same + 224 floats  (row 2r+1) -- lane stride 16 B, coalesced
//   stores float2 out[2*idx]                    -- lane stride 8 B, coalesced
// vs R1's 32 B lane-stride float4 pairs (50% per-instruction density).
//
// Traffic: 411 MB read + 103 MB write => ~82 us floor at 6.3 TB/s achievable.

#define TOTAL_ITEMS (32 * 64 * 112 * 56)  // 12,845,056 float4-input chunks

__global__ __launch_bounds__(256) void maxpool_2x2_kernel(
    const float* __restrict__ in, float* __restrict__ out) {
    const int total = TOTAL_ITEMS;
    const int stride = gridDim.x * blockDim.x;
    for (int idx = blockIdx.x * blockDim.x + threadIdx.x; idx < total; idx += stride) {
        const int r = idx / 56;  // row-pair index (global, plane-agnostic)
        // input offset of this chunk in row 2r:  4*idx + 224*r
        const float* src = in + (size_t)4 * idx + (size_t)224 * r;

        const float4 a = *reinterpret_cast<const float4*>(src);        // row 2r
        const float4 b = *reinterpret_cast<const float4*>(src + 224);  // row 2r+1

        float2 o;
        o.x = fmaxf(fmaxf(a.x, a.y), fmaxf(b.x, b.y));
        o.y = fmaxf(fmaxf(a.z, a.w), fmaxf(b.z, b.w));

        *reinterpret_cast<float2*>(out + (size_t)2 * idx) = o;
    }
}

extern "C" void kernel_launch(void* const* d_in, const int* in_sizes, int n_in,
                              void* d_out, int out_size, void* d_ws, size_t ws_size,
                              hipStream_t stream) {
    const float* X = (const float*)d_in[0];
    float* out = (float*)d_out;
    // 2048 blocks x 256 threads = 8 blocks/CU; ~24 grid-stride iterations each.
    maxpool_2x2_kernel<<<2048, 256, 0, stream>>>(X, out);
}